// Round 10
// baseline (509.798 us; speedup 1.0000x reference)
//
#include <hip/hip_runtime.h>
#include <hip/hip_bf16.h>
#include <hip/hip_fp16.h>
#include <math.h>

#define NN 100000
#define EE 1000000
#define GG 64
#define BN_EPS 1e-5f
#define CPB 16   // pooling chunks per graph
#define EB 4096  // edges per bucket-pass block
#define NBLK ((EE + EB - 1) / EB)   // 245
#define NBUCK ((NN + 511) / 512)    // 196 buckets of 512 nodes

typedef __attribute__((ext_vector_type(8))) short bf16x8;
typedef __attribute__((ext_vector_type(4))) float f32x4;

// float -> bf16 (RNE) and back, as raw shorts
__device__ inline short f2bf(float f) {
  unsigned u = __float_as_uint(f);
  u = u + 0x7fff + ((u >> 16) & 1);
  return (short)(u >> 16);
}
__device__ inline float bf2f(short h) {
  return __uint_as_float(((unsigned)(unsigned short)h) << 16);
}

// order-preserving float<->uint transform (for atomicMax on floats)
__device__ inline unsigned fenc(float f) {
  int b = __float_as_int(f);
  return (b < 0) ? ~(unsigned)b : ((unsigned)b | 0x80000000u);
}
__device__ inline float fdec(unsigned u) {
  int b = (u & 0x80000000u) ? (int)(u & 0x7fffffffu) : (int)~u;
  return __int_as_float(b);
}

// fp16 pair accumulate into two fp32 accs in ONE instr each (v_fma_mix)
__device__ inline void acc2(float& a0, float& a1, unsigned u) {
  asm("v_fma_mix_f32 %0, %2, 1.0, %0 op_sel:[0,0,0] op_sel_hi:[1,0,0]\n\t"
      "v_fma_mix_f32 %1, %2, 1.0, %1 op_sel:[1,0,0] op_sel_hi:[1,0,0]"
      : "+v"(a0), "+v"(a1)
      : "v"(u));
}
__device__ inline void acc8(float* a, uint4 u) {
  acc2(a[0], a[1], u.x);
  acc2(a[2], a[3], u.y);
  acc2(a[4], a[5], u.z);
  acc2(a[6], a[7], u.w);
}
__device__ inline uint4 zsel(uint4 u, int ok) {
  uint4 r;
  r.x = ok ? u.x : 0u;
  r.y = ok ? u.y : 0u;
  r.z = ok ? u.z : 0u;
  r.w = ok ? u.w : 0u;
  return r;
}

// ---------------- bucketed edge grouping ----------------
__global__ __launch_bounds__(256) void k_bhist(const int* __restrict__ dst,
                                               int* __restrict__ bhist, int E) {
  __shared__ int h[256];
  int t = threadIdx.x;
  h[t] = 0;
  __syncthreads();
  int base = blockIdx.x * EB;
#pragma unroll
  for (int j = 0; j < EB / 256; ++j) {
    int i = base + j * 256 + t;
    if (i < E) atomicAdd(&h[dst[i] >> 9], 1);
  }
  __syncthreads();
  bhist[blockIdx.x * 256 + t] = h[t];
}

__global__ __launch_bounds__(256) void k_bscan1(int* __restrict__ bhist,
                                                int* __restrict__ btot) {
  __shared__ int s[256];
  int bin = blockIdx.x, t = threadIdx.x;
  int v = (t < NBLK) ? bhist[t * 256 + bin] : 0;
  s[t] = v;
  __syncthreads();
  for (int o = 1; o < 256; o <<= 1) {
    int u = (t >= o) ? s[t - o] : 0;
    __syncthreads();
    s[t] += u;
    __syncthreads();
  }
  if (t < NBLK) bhist[t * 256 + bin] = s[t] - v;
  if (t == 255) btot[bin] = s[255];
}

__global__ __launch_bounds__(256) void k_bscan2(const int* __restrict__ btot,
                                                int* __restrict__ bstart) {
  __shared__ int s[256];
  int t = threadIdx.x;
  int v = btot[t];
  s[t] = v;
  __syncthreads();
  for (int o = 1; o < 256; o <<= 1) {
    int u = (t >= o) ? s[t - o] : 0;
    __syncthreads();
    s[t] += u;
    __syncthreads();
  }
  bstart[t] = s[t] - v;
}

__global__ __launch_bounds__(256) void k_bscat(const int* __restrict__ src,
                                               const int* __restrict__ dst,
                                               const int* __restrict__ bhist,
                                               const int* __restrict__ bstart,
                                               int2* __restrict__ pairs, int E) {
  __shared__ int h[256];
  __shared__ int base[256];
  int t = threadIdx.x;
  h[t] = 0;
  __syncthreads();
  int b0 = blockIdx.x * EB;
  int ds[EB / 256], rk[EB / 256];
#pragma unroll
  for (int j = 0; j < EB / 256; ++j) {
    int i = b0 + j * 256 + t;
    if (i < E) {
      int d = dst[i];
      ds[j] = d;
      rk[j] = atomicAdd(&h[d >> 9], 1);
    } else
      ds[j] = -1;
  }
  __syncthreads();
  base[t] = bstart[t] + bhist[blockIdx.x * 256 + t];
  __syncthreads();
#pragma unroll
  for (int j = 0; j < EB / 256; ++j) {
    int i = b0 + j * 256 + t;
    if (ds[j] >= 0) {
      int pos = base[ds[j] >> 9] + rk[j];
      pairs[pos] = make_int2(src[i], ds[j]);
    }
  }
}

__global__ __launch_bounds__(256) void k_bfill(const int2* __restrict__ pairs,
                                               const int* __restrict__ bstart,
                                               int* __restrict__ rowstart,
                                               int* __restrict__ eidx,
                                               float* __restrict__ dinv, int N,
                                               int E) {
  __shared__ int h[512];
  __shared__ int ex[512];
  __shared__ int ps[256];
  const int b = blockIdx.x;
  const int n0 = b << 9;
  const int e0 = bstart[b], e1 = bstart[b + 1];
  const int t = threadIdx.x;
  h[t] = 0;
  h[t + 256] = 0;
  __syncthreads();
  for (int i = e0 + t; i < e1; i += 256) atomicAdd(&h[pairs[i].y - n0], 1);
  __syncthreads();
  int v0 = h[2 * t], v1 = h[2 * t + 1];
  int sp = v0 + v1;
  ps[t] = sp;
  __syncthreads();
  for (int o = 1; o < 256; o <<= 1) {
    int u = (t >= o) ? ps[t - o] : 0;
    __syncthreads();
    ps[t] += u;
    __syncthreads();
  }
  int ex0 = ps[t] - sp;
  ex[2 * t] = ex0;
  ex[2 * t + 1] = ex0 + v0;
  __syncthreads();
  for (int i = t; i < 512; i += 256) {
    int node = n0 + i;
    if (node < N) {
      rowstart[node] = e0 + ex[i];
      dinv[node] = rsqrtf(1.0f + (float)h[i]);
    }
  }
  if (b == 0 && t == 0) rowstart[N] = E;
  __syncthreads();
  for (int i = e0 + t; i < e1; i += 256) {
    int2 p = pairs[i];
    int r = atomicAdd(&ex[p.y - n0], 1);
    eidx[e0 + r] = p.x;
  }
}

// ---------------- fused prep: wsplit + bnprep + gbounds + pool-zero ---------
__global__ __launch_bounds__(256) void k_prep(
    const float* __restrict__ W1, const float* __restrict__ W2,
    const float* __restrict__ W3, const float* __restrict__ Wg1,
    short* __restrict__ wt, const float* __restrict__ g1,
    const float* __restrict__ b1, const float* __restrict__ m1,
    const float* __restrict__ v1, const float* __restrict__ g2,
    const float* __restrict__ b2, const float* __restrict__ m2,
    const float* __restrict__ v2, float* __restrict__ s1,
    float* __restrict__ h1, float* __restrict__ s2, float* __restrict__ h2,
    const int* __restrict__ batch, int* __restrict__ gstart,
    float* __restrict__ pooledw, int N) {
  const int b = blockIdx.x, t = threadIdx.x;
  if (b < 192) {
    int i = b * 256 + t;
    const float* W;
    short *hi, *lo;
    int K, M, idx;
    if (i < 16384) {
      W = W1; hi = wt; lo = wt + 16384; K = 128; M = 128; idx = i;
    } else if (i < 32768) {
      W = W2; hi = wt + 32768; lo = wt + 49152; K = 128; M = 128; idx = i - 16384;
    } else if (i < 40960) {
      W = W3; hi = wt + 65536; lo = wt + 73728; K = 128; M = 64; idx = i - 32768;
    } else {
      W = Wg1; hi = wt + 81920; lo = wt + 90112; K = 64; M = 128; idx = i - 40960;
    }
    int k = idx / M, n = idx % M;
    float w = W[idx];
    short h = f2bf(w);
    hi[n * K + k] = h;
    lo[n * K + k] = f2bf(w - bf2f(h));
  } else if (b == 192) {
    if (t < 128) {
      float s = g1[t] * rsqrtf(v1[t] + BN_EPS);
      s1[t] = s;
      h1[t] = b1[t] - m1[t] * s;
    } else {
      int j = t - 128;
      float s = g2[j] * rsqrtf(v2[j] + BN_EPS);
      s2[j] = s;
      h2[j] = b2[j] - m2[j] * s;
    }
  } else {
    if (t <= GG) {
      int lo = 0, hi = N;
      while (lo < hi) {
        int mid = (lo + hi) >> 1;
        if (batch[mid] < t) lo = mid + 1;
        else hi = mid;
      }
      gstart[t] = lo;
    }
    for (int i = t; i < GG * 64 + GG + GG; i += 256) pooledw[i] = 0.f;
  }
}

// ---------------- MFMA split-bf16 GEMM, LDS-staged weights ------------------
// Round-9 refuted traffic theories; the mgemm symptom (nothing busy, occ
// ~25%) is per-block serial latency with too few resident blocks. This round:
// CTB=2 (32-col tiles) for the OUTH GEMMs -> LDS 52->17KB, fewer VGPRs,
// launch_bounds(256,4), grid x2 -> deeper block overlap. GATE keeps CTB=8
// (needs all 128 cols for its column reduction).
template <int K, int M, int CTB, int AIN, int DINV, int GATE, int OUTH>
__device__ __forceinline__ void mgemm_body(
    short* lds, const float* __restrict__ Xf, const short* __restrict__ Xhi,
    const short* __restrict__ Xlo, const short* __restrict__ Wthi,
    const short* __restrict__ Wtlo, const float* __restrict__ dinv,
    const float* __restrict__ gbias, const float* __restrict__ Wg2v,
    const float* __restrict__ bg2v, void* __restrict__ Y,
    float* __restrict__ gate, int nrows) {
  constexpr int NC = K / 32;
  constexpr int KP = K + 8;
  constexpr int R = 2;
  const int lane = threadIdx.x & 63;
  const int wave = threadIdx.x >> 6;
  const int m16 = lane & 15;
  const int quad = lane >> 4;
  const int rowbase = blockIdx.x * 128 + wave * 32;
  const int cbase = blockIdx.y * CTB * 16;

  bf16x8 ahi[R][NC], alo[R][NC];
#pragma unroll
  for (int t = 0; t < R; ++t) {
    const int arow = rowbase + t * 16 + m16;
    const bool rok = arow < nrows;
#pragma unroll
    for (int c = 0; c < NC; ++c) {
      const int k0 = c * 32 + quad * 8;
      if constexpr (AIN) {
        if (rok) {
          ahi[t][c] = *(const bf16x8*)(Xhi + (size_t)arow * K + k0);
          alo[t][c] = *(const bf16x8*)(Xlo + (size_t)arow * K + k0);
        } else {
          ahi[t][c] = bf16x8{0, 0, 0, 0, 0, 0, 0, 0};
          alo[t][c] = bf16x8{0, 0, 0, 0, 0, 0, 0, 0};
        }
      } else {
        float4 v0 = make_float4(0.f, 0.f, 0.f, 0.f), v1 = v0;
        if (rok) {
          v0 = *(const float4*)(Xf + (size_t)arow * K + k0);
          v1 = *(const float4*)(Xf + (size_t)arow * K + k0 + 4);
        }
        float vv[8] = {v0.x, v0.y, v0.z, v0.w, v1.x, v1.y, v1.z, v1.w};
#pragma unroll
        for (int j = 0; j < 8; ++j) {
          short h = f2bf(vv[j]);
          ahi[t][c][j] = h;
          alo[t][c][j] = f2bf(vv[j] - bf2f(h));
        }
      }
    }
  }

  // stage B panel into LDS (hi plane, then lo plane), padded rows
  {
    constexpr int ELEMS = CTB * 16 * K;
#pragma unroll
    for (int i = threadIdx.x * 8; i < ELEMS; i += 256 * 8) {
      const int r = i / K, c = i % K;
      *(bf16x8*)(&lds[r * KP + c]) =
          *(const bf16x8*)(Wthi + (size_t)(cbase + r) * K + c);
      *(bf16x8*)(&lds[CTB * 16 * KP + r * KP + c]) =
          *(const bf16x8*)(Wtlo + (size_t)(cbase + r) * K + c);
    }
  }

  float dv[R][4];
  if constexpr (DINV && !GATE) {
#pragma unroll
    for (int t = 0; t < R; ++t)
#pragma unroll
      for (int r = 0; r < 4; ++r) {
        int row = rowbase + t * 16 + quad * 4 + r;
        dv[t][r] = (row < nrows) ? dinv[row] : 0.f;
      }
  }

  float gp[R][4];
  if constexpr (GATE) {
#pragma unroll
    for (int t = 0; t < R; ++t)
#pragma unroll
      for (int r = 0; r < 4; ++r) gp[t][r] = 0.f;
  }

  __syncthreads();

  f32x4 accs[CTB][R];
#pragma unroll
  for (int ct = 0; ct < CTB; ++ct) {
    bf16x8 bhi[NC], blo[NC];
    const int wrow = (ct * 16 + m16) * KP + quad * 8;
#pragma unroll
    for (int c = 0; c < NC; ++c) {
      bhi[c] = *(const bf16x8*)(&lds[wrow + c * 32]);
      blo[c] = *(const bf16x8*)(&lds[CTB * 16 * KP + wrow + c * 32]);
    }
#pragma unroll
    for (int t = 0; t < R; ++t) {
      f32x4 acc = {0.f, 0.f, 0.f, 0.f};
#pragma unroll
      for (int c = 0; c < NC; ++c) {
        acc = __builtin_amdgcn_mfma_f32_16x16x32_bf16(ahi[t][c], bhi[c], acc, 0, 0, 0);
        acc = __builtin_amdgcn_mfma_f32_16x16x32_bf16(ahi[t][c], blo[c], acc, 0, 0, 0);
        acc = __builtin_amdgcn_mfma_f32_16x16x32_bf16(alo[t][c], bhi[c], acc, 0, 0, 0);
      }
      if constexpr (GATE) {
        const int col = cbase + ct * 16 + m16;
        const float gb = gbias[col], wg = Wg2v[col];
#pragma unroll
        for (int r = 0; r < 4; ++r) gp[t][r] += fmaxf(acc[r] + gb, 0.f) * wg;
      } else {
        accs[ct][t] = acc;
      }
    }
  }

  if constexpr (GATE) {
#pragma unroll
    for (int o = 1; o < 16; o <<= 1) {
#pragma unroll
      for (int t = 0; t < R; ++t)
#pragma unroll
        for (int r = 0; r < 4; ++r) gp[t][r] += __shfl_xor(gp[t][r], o, 64);
    }
    if (m16 == 0) {
      const float b2 = bg2v[0];
#pragma unroll
      for (int t = 0; t < R; ++t)
#pragma unroll
        for (int r = 0; r < 4; ++r) {
          const int row = rowbase + t * 16 + quad * 4 + r;
          if (row < nrows) gate[row] = gp[t][r] + b2;
        }
    }
  } else {
    // staged epilogue: regs -> LDS fp16 -> full-line global stores
    constexpr int COLS = CTB * 16;   // 32
    constexpr int SP = COLS + 8;
    __syncthreads();
#pragma unroll
    for (int ct = 0; ct < CTB; ++ct)
#pragma unroll
      for (int t = 0; t < R; ++t)
#pragma unroll
        for (int r = 0; r < 4; ++r) {
          const int row_l = wave * 32 + t * 16 + quad * 4 + r;
          float v = accs[ct][t][r];
          if constexpr (DINV) v *= dv[t][r];
          __half hv = __float2half(v);
          lds[row_l * SP + ct * 16 + m16] = *(short*)&hv;
        }
    __syncthreads();
    constexpr int TOT = 128 * COLS;
#pragma unroll
    for (int p = 0; p < TOT / (256 * 8); ++p) {
      const int idx8 = (p * 256 + threadIdx.x) * 8;
      const int row_l = idx8 / COLS;
      const int col0 = idx8 % COLS;
      const int grow = blockIdx.x * 128 + row_l;
      if (grow < nrows) {
        bf16x8 v = *(const bf16x8*)(&lds[row_l * SP + col0]);
        *(bf16x8*)((__half*)Y + (size_t)grow * M + cbase + col0) = v;
      }
    }
  }
}

#define MGEMM_ARGS                                                            \
  const float *Xf, const short *Xhi, const short *Xlo, const short *Wthi,     \
      const short *Wtlo, const float *dinv, const float *gbias,               \
      const float *Wg2v, const float *bg2v, void *Y, float *gate, int nrows

#define DEF_MGEMM(NAME, K, M, CTB, AIN, DINV, GATE, OUTH, WPE)                \
  __global__ __launch_bounds__(256, WPE) void NAME(MGEMM_ARGS) {              \
    __shared__ short lds[2 * CTB * 16 * (K + 8)];                             \
    mgemm_body<K, M, CTB, AIN, DINV, GATE, OUTH>(lds, Xf, Xhi, Xlo, Wthi,     \
                                                 Wtlo, dinv, gbias, Wg2v,     \
                                                 bg2v, Y, gate, nrows);       \
  }

DEF_MGEMM(k_mgemm1, 128, 128, 2, 0, 1, 0, 1, 4)  // LDS 17.4KB, 32-col tiles
DEF_MGEMM(k_mgemm2, 128, 128, 2, 1, 1, 0, 1, 4)
DEF_MGEMM(k_mgemm3, 128, 64, 2, 1, 1, 0, 1, 4)
DEF_MGEMM(k_mgemmg, 64, 128, 8, 0, 0, 1, 0, 3)   // LDS 36.9KB, full cols

// ---------------- GCN aggregation (round-6 dense layout) --------------------
template <int M, int EPI>
__device__ __forceinline__ void agg_body(
    const __half* __restrict__ hp, const int* __restrict__ rowstart,
    const int* __restrict__ eidx, const float* __restrict__ dinv,
    const float* __restrict__ bias, const float* __restrict__ bns,
    const float* __restrict__ bnh, float* __restrict__ outf,
    short* __restrict__ ohi, short* __restrict__ olo, int N) {
  constexpr int LPR = M / 8;
  constexpr int NPW = 64 / (2 * LPR);
  const int wv = (blockIdx.x * 256 + threadIdx.x) >> 6;
  const int lane = threadIdx.x & 63;
  const int grp = lane / (2 * LPR);
  const int slot = (lane / LPR) & 1;
  const int sub = lane % LPR;
  const int w = wv * NPW + grp;
  if (w >= N) return;
  const unsigned subo = (unsigned)sub * 16u;
  const float di = dinv[w];
  const int lo = rowstart[w], hi = rowstart[w + 1];
  const int hi1 = hi - 1;
  const char* hpb = (const char*)hp;
  float a[8] = {0.f, 0.f, 0.f, 0.f, 0.f, 0.f, 0.f, 0.f};

  int e = lo + slot;
  while (e < hi) {
    int idx[8], ss[8];
    uint4 uu[8];
#pragma unroll
    for (int p = 0; p < 8; ++p) {
      idx[p] = e + 2 * p;
      ss[p] = eidx[min(idx[p], hi1)];
    }
#pragma unroll
    for (int p = 0; p < 8; ++p)
      uu[p] = *(const uint4*)(hpb + ((unsigned)ss[p] * (unsigned)(M * 2) + subo));
#pragma unroll
    for (int p = 0; p < 8; ++p) {
      uu[p] = zsel(uu[p], idx[p] < hi);
      acc8(a, uu[p]);
    }
    e += 16;
  }
#pragma unroll
  for (int j = 0; j < 8; ++j) a[j] += __shfl_xor(a[j], LPR, 64);

  if (slot != 0) return;
  uint4 us = *(const uint4*)(hpb + ((unsigned)w * (unsigned)(M * 2) + subo));
  acc8(a, us);
  float4 b0 = *(const float4*)(bias + sub * 8);
  float4 b1 = *(const float4*)(bias + sub * 8 + 4);
  float r[8];
  r[0] = a[0] * di + b0.x;
  r[1] = a[1] * di + b0.y;
  r[2] = a[2] * di + b0.z;
  r[3] = a[3] * di + b0.w;
  r[4] = a[4] * di + b1.x;
  r[5] = a[5] * di + b1.y;
  r[6] = a[6] * di + b1.z;
  r[7] = a[7] * di + b1.w;
  if constexpr (EPI) {
    float4 s0 = *(const float4*)(bns + sub * 8);
    float4 s1 = *(const float4*)(bns + sub * 8 + 4);
    float4 h0 = *(const float4*)(bnh + sub * 8);
    float4 h1 = *(const float4*)(bnh + sub * 8 + 4);
    float sv[8] = {s0.x, s0.y, s0.z, s0.w, s1.x, s1.y, s1.z, s1.w};
    float hv[8] = {h0.x, h0.y, h0.z, h0.w, h1.x, h1.y, h1.z, h1.w};
    short hs[8], ls[8];
#pragma unroll
    for (int j = 0; j < 8; ++j) {
      float ev = fmaxf(r[j] * sv[j] + hv[j], 0.f);
      short hb = f2bf(ev);
      float res = ev - bf2f(hb);
      hs[j] = hb;
      ls[j] = (short)(__float_as_uint(res) >> 16);
    }
    *(short4*)(ohi + (size_t)w * M + sub * 8) = make_short4(hs[0], hs[1], hs[2], hs[3]);
    *(short4*)(ohi + (size_t)w * M + sub * 8 + 4) = make_short4(hs[4], hs[5], hs[6], hs[7]);
    *(short4*)(olo + (size_t)w * M + sub * 8) = make_short4(ls[0], ls[1], ls[2], ls[3]);
    *(short4*)(olo + (size_t)w * M + sub * 8 + 4) = make_short4(ls[4], ls[5], ls[6], ls[7]);
  } else {
    *(float4*)(outf + (size_t)w * M + sub * 8) = make_float4(r[0], r[1], r[2], r[3]);
    *(float4*)(outf + (size_t)w * M + sub * 8 + 4) = make_float4(r[4], r[5], r[6], r[7]);
  }
}

#define AGG_ARGS                                                              \
  const __half *hp, const int *rowstart, const int *eidx, const float *dinv,  \
      const float *bias, const float *bns, const float *bnh, float *outf,     \
      short *ohi, short *olo, int N

#define DEF_AGG(NAME, M, EPI)                                                 \
  __global__ __launch_bounds__(256) void NAME(AGG_ARGS) {                     \
    agg_body<M, EPI>(hp, rowstart, eidx, dinv, bias, bns, bnh, outf, ohi,     \
                     olo, N);                                                 \
  }

DEF_AGG(k_agg1, 128, 1)
DEF_AGG(k_agg2, 128, 1)
DEF_AGG(k_agg3, 64, 0)

// ---------------- pooling ----------------
__global__ __launch_bounds__(256) void k_pmax(const float* __restrict__ gate,
                                              const int* __restrict__ gstart,
                                              unsigned* __restrict__ gmaxu) {
  __shared__ unsigned red[256];
  const int g = blockIdx.x / CPB;
  const int c = blockIdx.x % CPB;
  const int lo = gstart[g], hi = gstart[g + 1];
  const int len = hi - lo;
  const int b0 = lo + (int)(((long long)len * c) / CPB);
  const int b1 = lo + (int)(((long long)len * (c + 1)) / CPB);
  unsigned mx = 0u;
  for (int i = b0 + threadIdx.x; i < b1; i += 256) mx = max(mx, fenc(gate[i]));
  red[threadIdx.x] = mx;
  __syncthreads();
  for (int o = 128; o; o >>= 1) {
    if (threadIdx.x < o)
      red[threadIdx.x] = max(red[threadIdx.x], red[threadIdx.x + o]);
    __syncthreads();
  }
  if (threadIdx.x == 0 && red[0] != 0u) atomicMax(&gmaxu[g], red[0]);
}

__global__ __launch_bounds__(256) void k_psum(const float* __restrict__ gate,
                                              const float* __restrict__ h3,
                                              const unsigned* __restrict__ gmaxu,
                                              const int* __restrict__ gstart,
                                              float* __restrict__ pooledw,
                                              float* __restrict__ ssum) {
  __shared__ float accs[4][64];
  __shared__ float ses[4];
  const int g = blockIdx.x / CPB;
  const int c = blockIdx.x % CPB;
  const int lo = gstart[g], hi = gstart[g + 1];
  const int len = hi - lo;
  const int b0 = lo + (int)(((long long)len * c) / CPB);
  const int b1 = lo + (int)(((long long)len * (c + 1)) / CPB);
  const int wave = threadIdx.x >> 6, lane = threadIdx.x & 63;
  const float m = fdec(gmaxu[g]);
  float acc = 0.f, se = 0.f;
  for (int i = b0 + wave; i < b1; i += 4) {
    float e = expf(gate[i] - m);
    acc += e * h3[(size_t)i * 64 + lane];
    se += e;
  }
  accs[wave][lane] = acc;
  if (lane == 0) ses[wave] = se;
  __syncthreads();
  if (threadIdx.x < 64) {
    float a = accs[0][threadIdx.x] + accs[1][threadIdx.x] +
              accs[2][threadIdx.x] + accs[3][threadIdx.x];
    if (a != 0.f) atomicAdd(&pooledw[g * 64 + threadIdx.x], a);
  }
  if (threadIdx.x == 64) {
    float s = ses[0] + ses[1] + ses[2] + ses[3];
    if (s != 0.f) atomicAdd(&ssum[g], s);
  }
}

// ---------------- head MLP ----------------
__global__ __launch_bounds__(256) void k_head(const float* __restrict__ pooledw,
                                              const float* __restrict__ ssum,
                                              const float* __restrict__ Wm1,
                                              const float* __restrict__ bm1,
                                              const float* __restrict__ Wm2,
                                              const float* __restrict__ bm2,
                                              float* __restrict__ out) {
  __shared__ float P[64 * 64];
  __shared__ float T[64 * 128];
  int tid = threadIdx.x;
  for (int i = tid; i < 4096; i += 256) {
    float s = ssum[i >> 6];
    P[i] = pooledw[i] * ((s > 0.f) ? 1.0f / s : 0.f);
  }
  __syncthreads();
  for (int e = tid; e < 8192; e += 256) {
    int r = e >> 7, c = e & 127;
    float a = bm1[c];
    for (int k = 0; k < 64; ++k) a += P[r * 64 + k] * Wm1[k * 128 + c];
    T[e] = fmaxf(a, 0.f);
  }
  __syncthreads();
  for (int e = tid; e < 4096; e += 256) {
    int r = e >> 6, c = e & 63;
    float a = bm2[c];
    for (int k = 0; k < 128; ++k) a += T[r * 128 + k] * Wm2[k * 64 + c];
    out[e] = a;
  }
}

extern "C" void kernel_launch(void* const* d_in, const int* in_sizes, int n_in,
                              void* d_out, int out_size, void* d_ws,
                              size_t ws_size, hipStream_t stream) {
  const int N = NN, E = EE;
  const float* x = (const float*)d_in[0];
  const int* ei = (const int*)d_in[1];
  const int* batch = (const int*)d_in[2];
  const float* W1 = (const float*)d_in[3];
  const float* b1 = (const float*)d_in[4];
  const float* W2 = (const float*)d_in[5];
  const float* b2 = (const float*)d_in[6];
  const float* W3 = (const float*)d_in[7];
  const float* b3 = (const float*)d_in[8];
  const float* g1 = (const float*)d_in[9];
  const float* beta1 = (const float*)d_in[10];
  const float* g2 = (const float*)d_in[11];
  const float* beta2 = (const float*)d_in[12];
  const float* mean1 = (const float*)d_in[13];
  const float* var1 = (const float*)d_in[14];
  const float* mean2 = (const float*)d_in[15];
  const float* var2 = (const float*)d_in[16];
  const float* Wg1 = (const float*)d_in[17];
  const float* bg1 = (const float*)d_in[18];
  const float* Wg2 = (const float*)d_in[19];
  const float* bg2 = (const float*)d_in[20];
  const float* Wm1 = (const float*)d_in[21];
  const float* bm1 = (const float*)d_in[22];
  const float* Wm2 = (const float*)d_in[23];
  const float* bm2 = (const float*)d_in[24];
  float* out = (float*)d_out;

  const int* src = ei;
  const int* dst = ei + E;

  char* wsb = (char*)d_ws;
  size_t off = 0;
  auto alloc = [&](size_t elems) -> void* {
    void* p = wsb + off;
    off += elems * 4;
    return p;
  };
  int* rowstart = (int*)alloc(N + 4);
  int* eidx = (int*)alloc(E);
  int2* pairs = (int2*)alloc((size_t)E * 2);
  int* bhist = (int*)alloc(NBLK * 256 + 256);
  int* btot = (int*)alloc(256);
  int* bstart = (int*)alloc(256);
  float* dinv = (float*)alloc(N);
  float* gate = (float*)alloc(N);
  __half* hbuf = (__half*)alloc((size_t)N * 64);  // fp16 N x 128 plane
  short* ahi_p = (short*)alloc((size_t)N * 64);   // bf16-hi N x 128 plane
  short* alo_p = (short*)alloc((size_t)N * 64);   // bf16-lo N x 128 plane
  float* fbuf = (float*)alloc((size_t)N * 64);    // fp32 N x 64 (h3)
  short* wt = (short*)alloc(49152);
  float* bn1s = (float*)alloc(128);
  float* bn1h = (float*)alloc(128);
  float* bn2s = (float*)alloc(128);
  float* bn2h = (float*)alloc(128);
  float* pooledw = (float*)alloc(GG * 64);
  float* ssum = (float*)alloc(GG);
  unsigned* gmaxu = (unsigned*)alloc(GG);
  int* gstart = (int*)alloc(GG + 4);
  (void)ws_size;
  (void)n_in;
  (void)in_sizes;
  (void)out_size;

  // CSR build
  k_bhist<<<NBLK, 256, 0, stream>>>(dst, bhist, E);
  k_bscan1<<<256, 256, 0, stream>>>(bhist, btot);
  k_bscan2<<<1, 256, 0, stream>>>(btot, bstart);
  k_bscat<<<NBLK, 256, 0, stream>>>(src, dst, bhist, bstart, pairs, E);
  k_bfill<<<NBUCK, 256, 0, stream>>>(pairs, bstart, rowstart, eidx, dinv, N, E);

  // fused prep (wsplit + bnprep + gbounds + pool zero)
  k_prep<<<194, 256, 0, stream>>>(W1, W2, W3, Wg1, wt, g1, beta1, mean1, var1,
                                  g2, beta2, mean2, var2, bn1s, bn1h, bn2s,
                                  bn2h, batch, gstart, pooledw, N);

  const int gbb = (N + 127) / 128;
  const int ab128 = (N + 7) / 8;
  const int ab64 = (N + 15) / 16;

  // Layer 1
  k_mgemm1<<<dim3(gbb, 4), 256, 0, stream>>>(
      x, nullptr, nullptr, wt, wt + 16384, dinv, nullptr, nullptr, nullptr,
      hbuf, nullptr, N);
  k_agg1<<<ab128, 256, 0, stream>>>(hbuf, rowstart, eidx, dinv, b1, bn1s,
                                    bn1h, nullptr, ahi_p, alo_p, N);

  // Layer 2
  k_mgemm2<<<dim3(gbb, 4), 256, 0, stream>>>(
      nullptr, ahi_p, alo_p, wt + 32768, wt + 49152, dinv, nullptr, nullptr,
      nullptr, hbuf, nullptr, N);
  k_agg2<<<ab128, 256, 0, stream>>>(hbuf, rowstart, eidx, dinv, b2, bn2s,
                                    bn2h, nullptr, ahi_p, alo_p, N);

  // Layer 3 (M=64)
  k_mgemm3<<<dim3(gbb, 2), 256, 0, stream>>>(
      nullptr, ahi_p, alo_p, wt + 65536, wt + 73728, dinv, nullptr, nullptr,
      nullptr, hbuf, nullptr, N);
  k_agg3<<<ab64, 256, 0, stream>>>(hbuf, rowstart, eidx, dinv, b3, nullptr,
                                   nullptr, fbuf, nullptr, nullptr, N);

  // gate = relu(h3@Wg1+bg1)@Wg2+bg2 (fused epilogue)
  k_mgemmg<<<dim3(gbb, 1), 256, 0, stream>>>(
      fbuf, nullptr, nullptr, wt + 81920, wt + 90112, nullptr, bg1, Wg2, bg2,
      nullptr, gate, N);

  // softmax pooling
  k_pmax<<<GG * CPB, 256, 0, stream>>>(gate, gstart, gmaxu);
  k_psum<<<GG * CPB, 256, 0, stream>>>(gate, fbuf, gmaxu, gstart, pooledw,
                                       ssum);

  // head MLP
  k_head<<<1, 256, 0, stream>>>(pooledw, ssum, Wm1, bm1, Wm2, bm2, out);
}

// Round 11
// 455.634 us; speedup vs baseline: 1.1189x; 1.1189x over previous
//
#include <hip/hip_runtime.h>
#include <hip/hip_bf16.h>
#include <hip/hip_fp16.h>
#include <math.h>

#define NN 100000
#define EE 1000000
#define GG 64
#define BN_EPS 1e-5f
#define CPB 16   // pooling chunks per graph
#define EB 4096  // edges per bucket-pass block
#define NBLK ((EE + EB - 1) / EB)   // 245
#define NBUCK ((NN + 511) / 512)    // 196 buckets of 512 nodes

typedef __attribute__((ext_vector_type(8))) short bf16x8;
typedef __attribute__((ext_vector_type(4))) float f32x4;

// float -> bf16 (RNE) and back, as raw shorts
__device__ inline short f2bf(float f) {
  unsigned u = __float_as_uint(f);
  u = u + 0x7fff + ((u >> 16) & 1);
  return (short)(u >> 16);
}
__device__ inline float bf2f(short h) {
  return __uint_as_float(((unsigned)(unsigned short)h) << 16);
}

// order-preserving float<->uint transform (for atomicMax on floats)
__device__ inline unsigned fenc(float f) {
  int b = __float_as_int(f);
  return (b < 0) ? ~(unsigned)b : ((unsigned)b | 0x80000000u);
}
__device__ inline float fdec(unsigned u) {
  int b = (u & 0x80000000u) ? (int)(u & 0x7fffffffu) : (int)~u;
  return __int_as_float(b);
}

// fp16 pair accumulate into two fp32 accs in ONE instr each (v_fma_mix)
__device__ inline void acc2(float& a0, float& a1, unsigned u) {
  asm("v_fma_mix_f32 %0, %2, 1.0, %0 op_sel:[0,0,0] op_sel_hi:[1,0,0]\n\t"
      "v_fma_mix_f32 %1, %2, 1.0, %1 op_sel:[1,0,0] op_sel_hi:[1,0,0]"
      : "+v"(a0), "+v"(a1)
      : "v"(u));
}
__device__ inline void acc8(float* a, uint4 u) {
  acc2(a[0], a[1], u.x);
  acc2(a[2], a[3], u.y);
  acc2(a[4], a[5], u.z);
  acc2(a[6], a[7], u.w);
}
__device__ inline uint4 zsel(uint4 u, int ok) {
  uint4 r;
  r.x = ok ? u.x : 0u;
  r.y = ok ? u.y : 0u;
  r.z = ok ? u.z : 0u;
  r.w = ok ? u.w : 0u;
  return r;
}

// ---------------- bucketed edge grouping ----------------
__global__ __launch_bounds__(256) void k_bhist(const int* __restrict__ dst,
                                               int* __restrict__ bhist, int E) {
  __shared__ int h[256];
  int t = threadIdx.x;
  h[t] = 0;
  __syncthreads();
  int base = blockIdx.x * EB;
#pragma unroll
  for (int j = 0; j < EB / 256; ++j) {
    int i = base + j * 256 + t;
    if (i < E) atomicAdd(&h[dst[i] >> 9], 1);
  }
  __syncthreads();
  bhist[blockIdx.x * 256 + t] = h[t];
}

__global__ __launch_bounds__(256) void k_bscan1(int* __restrict__ bhist,
                                                int* __restrict__ btot) {
  __shared__ int s[256];
  int bin = blockIdx.x, t = threadIdx.x;
  int v = (t < NBLK) ? bhist[t * 256 + bin] : 0;
  s[t] = v;
  __syncthreads();
  for (int o = 1; o < 256; o <<= 1) {
    int u = (t >= o) ? s[t - o] : 0;
    __syncthreads();
    s[t] += u;
    __syncthreads();
  }
  if (t < NBLK) bhist[t * 256 + bin] = s[t] - v;
  if (t == 255) btot[bin] = s[255];
}

__global__ __launch_bounds__(256) void k_bscan2(const int* __restrict__ btot,
                                                int* __restrict__ bstart) {
  __shared__ int s[256];
  int t = threadIdx.x;
  int v = btot[t];
  s[t] = v;
  __syncthreads();
  for (int o = 1; o < 256; o <<= 1) {
    int u = (t >= o) ? s[t - o] : 0;
    __syncthreads();
    s[t] += u;
    __syncthreads();
  }
  bstart[t] = s[t] - v;
}

__global__ __launch_bounds__(256) void k_bscat(const int* __restrict__ src,
                                               const int* __restrict__ dst,
                                               const int* __restrict__ bhist,
                                               const int* __restrict__ bstart,
                                               int2* __restrict__ pairs, int E) {
  __shared__ int h[256];
  __shared__ int base[256];
  int t = threadIdx.x;
  h[t] = 0;
  __syncthreads();
  int b0 = blockIdx.x * EB;
  int ds[EB / 256], rk[EB / 256];
#pragma unroll
  for (int j = 0; j < EB / 256; ++j) {
    int i = b0 + j * 256 + t;
    if (i < E) {
      int d = dst[i];
      ds[j] = d;
      rk[j] = atomicAdd(&h[d >> 9], 1);
    } else
      ds[j] = -1;
  }
  __syncthreads();
  base[t] = bstart[t] + bhist[blockIdx.x * 256 + t];
  __syncthreads();
#pragma unroll
  for (int j = 0; j < EB / 256; ++j) {
    int i = b0 + j * 256 + t;
    if (ds[j] >= 0) {
      int pos = base[ds[j] >> 9] + rk[j];
      pairs[pos] = make_int2(src[i], ds[j]);
    }
  }
}

__global__ __launch_bounds__(256) void k_bfill(const int2* __restrict__ pairs,
                                               const int* __restrict__ bstart,
                                               int* __restrict__ rowstart,
                                               int* __restrict__ eidx,
                                               float* __restrict__ dinv, int N,
                                               int E) {
  __shared__ int h[512];
  __shared__ int ex[512];
  __shared__ int ps[256];
  const int b = blockIdx.x;
  const int n0 = b << 9;
  const int e0 = bstart[b], e1 = bstart[b + 1];
  const int t = threadIdx.x;
  h[t] = 0;
  h[t + 256] = 0;
  __syncthreads();
  for (int i = e0 + t; i < e1; i += 256) atomicAdd(&h[pairs[i].y - n0], 1);
  __syncthreads();
  int v0 = h[2 * t], v1 = h[2 * t + 1];
  int sp = v0 + v1;
  ps[t] = sp;
  __syncthreads();
  for (int o = 1; o < 256; o <<= 1) {
    int u = (t >= o) ? ps[t - o] : 0;
    __syncthreads();
    ps[t] += u;
    __syncthreads();
  }
  int ex0 = ps[t] - sp;
  ex[2 * t] = ex0;
  ex[2 * t + 1] = ex0 + v0;
  __syncthreads();
  for (int i = t; i < 512; i += 256) {
    int node = n0 + i;
    if (node < N) {
      rowstart[node] = e0 + ex[i];
      dinv[node] = rsqrtf(1.0f + (float)h[i]);
    }
  }
  if (b == 0 && t == 0) rowstart[N] = E;
  __syncthreads();
  for (int i = e0 + t; i < e1; i += 256) {
    int2 p = pairs[i];
    int r = atomicAdd(&ex[p.y - n0], 1);
    eidx[e0 + r] = p.x;
  }
}

// ---------------- fused prep: wsplit + bnprep + gbounds + pool-zero ---------
__global__ __launch_bounds__(256) void k_prep(
    const float* __restrict__ W1, const float* __restrict__ W2,
    const float* __restrict__ W3, const float* __restrict__ Wg1,
    short* __restrict__ wt, const float* __restrict__ g1,
    const float* __restrict__ b1, const float* __restrict__ m1,
    const float* __restrict__ v1, const float* __restrict__ g2,
    const float* __restrict__ b2, const float* __restrict__ m2,
    const float* __restrict__ v2, float* __restrict__ s1,
    float* __restrict__ h1, float* __restrict__ s2, float* __restrict__ h2,
    const int* __restrict__ batch, int* __restrict__ gstart,
    float* __restrict__ pooledw, int N) {
  const int b = blockIdx.x, t = threadIdx.x;
  if (b < 192) {
    int i = b * 256 + t;
    const float* W;
    short *hi, *lo;
    int K, M, idx;
    if (i < 16384) {
      W = W1; hi = wt; lo = wt + 16384; K = 128; M = 128; idx = i;
    } else if (i < 32768) {
      W = W2; hi = wt + 32768; lo = wt + 49152; K = 128; M = 128; idx = i - 16384;
    } else if (i < 40960) {
      W = W3; hi = wt + 65536; lo = wt + 73728; K = 128; M = 64; idx = i - 32768;
    } else {
      W = Wg1; hi = wt + 81920; lo = wt + 90112; K = 64; M = 128; idx = i - 40960;
    }
    int k = idx / M, n = idx % M;
    float w = W[idx];
    short h = f2bf(w);
    hi[n * K + k] = h;
    lo[n * K + k] = f2bf(w - bf2f(h));
  } else if (b == 192) {
    if (t < 128) {
      float s = g1[t] * rsqrtf(v1[t] + BN_EPS);
      s1[t] = s;
      h1[t] = b1[t] - m1[t] * s;
    } else {
      int j = t - 128;
      float s = g2[j] * rsqrtf(v2[j] + BN_EPS);
      s2[j] = s;
      h2[j] = b2[j] - m2[j] * s;
    }
  } else {
    if (t <= GG) {
      int lo = 0, hi = N;
      while (lo < hi) {
        int mid = (lo + hi) >> 1;
        if (batch[mid] < t) lo = mid + 1;
        else hi = mid;
      }
      gstart[t] = lo;
    }
    for (int i = t; i < GG * 64 + GG + GG; i += 256) pooledw[i] = 0.f;
  }
}

// ---------------- MFMA split-bf16 GEMM (round-6 config, CTB=4) --------------
template <int K, int M, int CTB, int AIN, int DINV, int OUTH>
__device__ __forceinline__ void mgemm_body(
    short* lds, const float* __restrict__ Xf, const short* __restrict__ Xhi,
    const short* __restrict__ Xlo, const short* __restrict__ Wthi,
    const short* __restrict__ Wtlo, const float* __restrict__ dinv,
    void* __restrict__ Y, int nrows) {
  constexpr int NC = K / 32;
  constexpr int KP = K + 8;
  constexpr int R = 2;
  const int lane = threadIdx.x & 63;
  const int wave = threadIdx.x >> 6;
  const int m16 = lane & 15;
  const int quad = lane >> 4;
  const int rowbase = blockIdx.x * 128 + wave * 32;
  const int cbase = blockIdx.y * CTB * 16;

  bf16x8 ahi[R][NC], alo[R][NC];
#pragma unroll
  for (int t = 0; t < R; ++t) {
    const int arow = rowbase + t * 16 + m16;
    const bool rok = arow < nrows;
#pragma unroll
    for (int c = 0; c < NC; ++c) {
      const int k0 = c * 32 + quad * 8;
      if constexpr (AIN) {
        if (rok) {
          ahi[t][c] = *(const bf16x8*)(Xhi + (size_t)arow * K + k0);
          alo[t][c] = *(const bf16x8*)(Xlo + (size_t)arow * K + k0);
        } else {
          ahi[t][c] = bf16x8{0, 0, 0, 0, 0, 0, 0, 0};
          alo[t][c] = bf16x8{0, 0, 0, 0, 0, 0, 0, 0};
        }
      } else {
        float4 v0 = make_float4(0.f, 0.f, 0.f, 0.f), v1 = v0;
        if (rok) {
          v0 = *(const float4*)(Xf + (size_t)arow * K + k0);
          v1 = *(const float4*)(Xf + (size_t)arow * K + k0 + 4);
        }
        float vv[8] = {v0.x, v0.y, v0.z, v0.w, v1.x, v1.y, v1.z, v1.w};
#pragma unroll
        for (int j = 0; j < 8; ++j) {
          short h = f2bf(vv[j]);
          ahi[t][c][j] = h;
          alo[t][c][j] = f2bf(vv[j] - bf2f(h));
        }
      }
    }
  }

  // stage B panel into LDS (hi plane, then lo plane), padded rows
  {
    constexpr int ELEMS = CTB * 16 * K;
#pragma unroll
    for (int i = threadIdx.x * 8; i < ELEMS; i += 256 * 8) {
      const int r = i / K, c = i % K;
      *(bf16x8*)(&lds[r * KP + c]) =
          *(const bf16x8*)(Wthi + (size_t)(cbase + r) * K + c);
      *(bf16x8*)(&lds[CTB * 16 * KP + r * KP + c]) =
          *(const bf16x8*)(Wtlo + (size_t)(cbase + r) * K + c);
    }
  }

  float dv[R][4];
  if constexpr (DINV) {
#pragma unroll
    for (int t = 0; t < R; ++t)
#pragma unroll
      for (int r = 0; r < 4; ++r) {
        int row = rowbase + t * 16 + quad * 4 + r;
        dv[t][r] = (row < nrows) ? dinv[row] : 0.f;
      }
  }

  __syncthreads();

  f32x4 accs[CTB][R];
#pragma unroll
  for (int ct = 0; ct < CTB; ++ct) {
    bf16x8 bhi[NC], blo[NC];
    const int wrow = (ct * 16 + m16) * KP + quad * 8;
#pragma unroll
    for (int c = 0; c < NC; ++c) {
      bhi[c] = *(const bf16x8*)(&lds[wrow + c * 32]);
      blo[c] = *(const bf16x8*)(&lds[CTB * 16 * KP + wrow + c * 32]);
    }
#pragma unroll
    for (int t = 0; t < R; ++t) {
      f32x4 acc = {0.f, 0.f, 0.f, 0.f};
#pragma unroll
      for (int c = 0; c < NC; ++c) {
        acc = __builtin_amdgcn_mfma_f32_16x16x32_bf16(ahi[t][c], bhi[c], acc, 0, 0, 0);
        acc = __builtin_amdgcn_mfma_f32_16x16x32_bf16(ahi[t][c], blo[c], acc, 0, 0, 0);
        acc = __builtin_amdgcn_mfma_f32_16x16x32_bf16(alo[t][c], bhi[c], acc, 0, 0, 0);
      }
      accs[ct][t] = acc;
    }
  }

  // staged epilogue: regs -> LDS fp16 -> full-line global stores
  constexpr int COLS = CTB * 16;   // 64
  constexpr int SP = COLS + 8;
  __syncthreads();
#pragma unroll
  for (int ct = 0; ct < CTB; ++ct)
#pragma unroll
    for (int t = 0; t < R; ++t)
#pragma unroll
      for (int r = 0; r < 4; ++r) {
        const int row_l = wave * 32 + t * 16 + quad * 4 + r;
        float v = accs[ct][t][r];
        if constexpr (DINV) v *= dv[t][r];
        __half hv = __float2half(v);
        lds[row_l * SP + ct * 16 + m16] = *(short*)&hv;
      }
  __syncthreads();
  constexpr int TOT = 128 * COLS;
#pragma unroll
  for (int p = 0; p < TOT / (256 * 8); ++p) {
    const int idx8 = (p * 256 + threadIdx.x) * 8;
    const int row_l = idx8 / COLS;
    const int col0 = idx8 % COLS;
    const int grow = blockIdx.x * 128 + row_l;
    if (grow < nrows) {
      bf16x8 v = *(const bf16x8*)(&lds[row_l * SP + col0]);
      *(bf16x8*)((__half*)Y + (size_t)grow * M + cbase + col0) = v;
    }
  }
}

#define MGEMM_ARGS                                                            \
  const float *Xf, const short *Xhi, const short *Xlo, const short *Wthi,     \
      const short *Wtlo, const float *dinv, void *Y, int nrows

#define DEF_MGEMM(NAME, K, M, CTB, AIN, DINV, OUTH)                           \
  __global__ __launch_bounds__(256, 3) void NAME(MGEMM_ARGS) {                \
    __shared__ short lds[2 * CTB * 16 * (K + 8)];                             \
    mgemm_body<K, M, CTB, AIN, DINV, OUTH>(lds, Xf, Xhi, Xlo, Wthi, Wtlo,     \
                                           dinv, Y, nrows);                   \
  }

DEF_MGEMM(k_mgemm1, 128, 128, 4, 0, 1, 1)
DEF_MGEMM(k_mgemm2, 128, 128, 4, 1, 1, 1)
DEF_MGEMM(k_mgemm3, 128, 64, 4, 1, 1, 1)

// ---------------- GCN aggregation (round-6 dense layout) --------------------
template <int M, int EPI>
__device__ __forceinline__ void agg_body(
    const __half* __restrict__ hp, const int* __restrict__ rowstart,
    const int* __restrict__ eidx, const float* __restrict__ dinv,
    const float* __restrict__ bias, const float* __restrict__ bns,
    const float* __restrict__ bnh, float* __restrict__ outf,
    short* __restrict__ ohi, short* __restrict__ olo, int N) {
  constexpr int LPR = M / 8;
  constexpr int NPW = 64 / (2 * LPR);
  const int wv = (blockIdx.x * 256 + threadIdx.x) >> 6;
  const int lane = threadIdx.x & 63;
  const int grp = lane / (2 * LPR);
  const int slot = (lane / LPR) & 1;
  const int sub = lane % LPR;
  const int w = wv * NPW + grp;
  if (w >= N) return;
  const unsigned subo = (unsigned)sub * 16u;
  const float di = dinv[w];
  const int lo = rowstart[w], hi = rowstart[w + 1];
  const int hi1 = hi - 1;
  const char* hpb = (const char*)hp;
  float a[8] = {0.f, 0.f, 0.f, 0.f, 0.f, 0.f, 0.f, 0.f};

  int e = lo + slot;
  while (e < hi) {
    int idx[8], ss[8];
    uint4 uu[8];
#pragma unroll
    for (int p = 0; p < 8; ++p) {
      idx[p] = e + 2 * p;
      ss[p] = eidx[min(idx[p], hi1)];
    }
#pragma unroll
    for (int p = 0; p < 8; ++p)
      uu[p] = *(const uint4*)(hpb + ((unsigned)ss[p] * (unsigned)(M * 2) + subo));
#pragma unroll
    for (int p = 0; p < 8; ++p) {
      uu[p] = zsel(uu[p], idx[p] < hi);
      acc8(a, uu[p]);
    }
    e += 16;
  }
#pragma unroll
  for (int j = 0; j < 8; ++j) a[j] += __shfl_xor(a[j], LPR, 64);

  if (slot != 0) return;
  uint4 us = *(const uint4*)(hpb + ((unsigned)w * (unsigned)(M * 2) + subo));
  acc8(a, us);
  float4 b0 = *(const float4*)(bias + sub * 8);
  float4 b1 = *(const float4*)(bias + sub * 8 + 4);
  float r[8];
  r[0] = a[0] * di + b0.x;
  r[1] = a[1] * di + b0.y;
  r[2] = a[2] * di + b0.z;
  r[3] = a[3] * di + b0.w;
  r[4] = a[4] * di + b1.x;
  r[5] = a[5] * di + b1.y;
  r[6] = a[6] * di + b1.z;
  r[7] = a[7] * di + b1.w;
  if constexpr (EPI) {
    float4 s0 = *(const float4*)(bns + sub * 8);
    float4 s1 = *(const float4*)(bns + sub * 8 + 4);
    float4 h0 = *(const float4*)(bnh + sub * 8);
    float4 h1 = *(const float4*)(bnh + sub * 8 + 4);
    float sv[8] = {s0.x, s0.y, s0.z, s0.w, s1.x, s1.y, s1.z, s1.w};
    float hv[8] = {h0.x, h0.y, h0.z, h0.w, h1.x, h1.y, h1.z, h1.w};
    short hs[8], ls[8];
#pragma unroll
    for (int j = 0; j < 8; ++j) {
      float ev = fmaxf(r[j] * sv[j] + hv[j], 0.f);
      short hb = f2bf(ev);
      float res = ev - bf2f(hb);
      hs[j] = hb;
      ls[j] = (short)(__float_as_uint(res) >> 16);
    }
    *(short4*)(ohi + (size_t)w * M + sub * 8) = make_short4(hs[0], hs[1], hs[2], hs[3]);
    *(short4*)(ohi + (size_t)w * M + sub * 8 + 4) = make_short4(hs[4], hs[5], hs[6], hs[7]);
    *(short4*)(olo + (size_t)w * M + sub * 8) = make_short4(ls[0], ls[1], ls[2], ls[3]);
    *(short4*)(olo + (size_t)w * M + sub * 8 + 4) = make_short4(ls[4], ls[5], ls[6], ls[7]);
  } else {
    *(float4*)(outf + (size_t)w * M + sub * 8) = make_float4(r[0], r[1], r[2], r[3]);
    *(float4*)(outf + (size_t)w * M + sub * 8 + 4) = make_float4(r[4], r[5], r[6], r[7]);
  }
}

#define AGG_ARGS                                                              \
  const __half *hp, const int *rowstart, const int *eidx, const float *dinv,  \
      const float *bias, const float *bns, const float *bnh, float *outf,     \
      short *ohi, short *olo, int N

#define DEF_AGG(NAME, M, EPI)                                                 \
  __global__ __launch_bounds__(256) void NAME(AGG_ARGS) {                     \
    agg_body<M, EPI>(hp, rowstart, eidx, dinv, bias, bns, bnh, outf, ohi,     \
                     olo, N);                                                 \
  }

DEF_AGG(k_agg1, 128, 1)
DEF_AGG(k_agg2, 128, 1)

// ---------------- agg3 + fused gate MLP -------------------------------------
// M=64 aggregation (writes fbuf for k_psum) PLUS the gate head fused in:
// each block's 16 nodes form exactly one MFMA M-tile. Slot-0 lanes stash
// their r[8] as bf16 hi/lo in LDS; after a barrier wave 0 runs the identical
// mgemmg pipeline (B = wt Wg1 panel, hot in L2; 8 ct x (2x3) MFMA; relu+Wg2
// column-reduce) and writes gate[]. Eliminates the k_mgemmg dispatch and its
// full fbuf re-read. Numerics identical to mgemmg's AIN=0 path (RNE hi/lo).
__global__ __launch_bounds__(256) void k_agg3g(
    const __half* __restrict__ hp, const int* __restrict__ rowstart,
    const int* __restrict__ eidx, const float* __restrict__ dinv,
    const float* __restrict__ bias, const short* __restrict__ wg1hi,
    const short* __restrict__ wg1lo, const float* __restrict__ bg1,
    const float* __restrict__ Wg2v, const float* __restrict__ bg2v,
    float* __restrict__ outf, float* __restrict__ gate, int N) {
  __shared__ short Ahi[16][72];
  __shared__ short Alo[16][72];
  const int lane = threadIdx.x & 63;
  const int wv = threadIdx.x >> 6;
  const int grp = lane >> 4;          // node group in wave (0..3)
  const int slot = (lane >> 3) & 1;   // edge slot
  const int sub = lane & 7;           // 16B segment of 128B row
  const int node_l = wv * 4 + grp;    // 0..15
  const int w = blockIdx.x * 16 + node_l;
  const bool valid = w < N;

  // zero A planes so invalid nodes contribute zero rows to the MFMA
  for (int i = threadIdx.x; i < 16 * 72; i += 256) {
    (&Ahi[0][0])[i] = 0;
    (&Alo[0][0])[i] = 0;
  }
  __syncthreads();

  const unsigned subo = (unsigned)sub * 16u;
  const float di = valid ? dinv[w] : 0.f;
  const int lo = valid ? rowstart[w] : 0;
  const int hi = valid ? rowstart[w + 1] : 0;
  const int hi1 = hi - 1;
  const char* hpb = (const char*)hp;
  float a[8] = {0.f, 0.f, 0.f, 0.f, 0.f, 0.f, 0.f, 0.f};

  int e = lo + slot;
  while (e < hi) {
    int idx[8], ss[8];
    uint4 uu[8];
#pragma unroll
    for (int p = 0; p < 8; ++p) {
      idx[p] = e + 2 * p;
      ss[p] = eidx[min(idx[p], hi1)];
    }
#pragma unroll
    for (int p = 0; p < 8; ++p)
      uu[p] = *(const uint4*)(hpb + ((unsigned)ss[p] * 128u + subo));
#pragma unroll
    for (int p = 0; p < 8; ++p) {
      uu[p] = zsel(uu[p], idx[p] < hi);
      acc8(a, uu[p]);
    }
    e += 16;
  }
#pragma unroll
  for (int j = 0; j < 8; ++j) a[j] += __shfl_xor(a[j], 8, 64);

  if (slot == 0 && valid) {
    uint4 us = *(const uint4*)(hpb + ((unsigned)w * 128u + subo));
    acc8(a, us);
    float4 b0 = *(const float4*)(bias + sub * 8);
    float4 b1 = *(const float4*)(bias + sub * 8 + 4);
    float r[8];
    r[0] = a[0] * di + b0.x;
    r[1] = a[1] * di + b0.y;
    r[2] = a[2] * di + b0.z;
    r[3] = a[3] * di + b0.w;
    r[4] = a[4] * di + b1.x;
    r[5] = a[5] * di + b1.y;
    r[6] = a[6] * di + b1.z;
    r[7] = a[7] * di + b1.w;
    *(float4*)(outf + (size_t)w * 64 + sub * 8) =
        make_float4(r[0], r[1], r[2], r[3]);
    *(float4*)(outf + (size_t)w * 64 + sub * 8 + 4) =
        make_float4(r[4], r[5], r[6], r[7]);
    // bf16 hi/lo split (RNE both, matching mgemmg's AIN=0 path)
#pragma unroll
    for (int j = 0; j < 8; ++j) {
      short h = f2bf(r[j]);
      Ahi[node_l][sub * 8 + j] = h;
      Alo[node_l][sub * 8 + j] = f2bf(r[j] - bf2f(h));
    }
  }
  __syncthreads();

  if (wv != 0) return;
  // gate GEMM for this block's 16 nodes (one wave, mgemmg pipeline)
  const int m16 = lane & 15;
  const int quad = lane >> 4;
  bf16x8 fa_hi[2], fa_lo[2];
#pragma unroll
  for (int c = 0; c < 2; ++c) {
    fa_hi[c] = *(const bf16x8*)(&Ahi[m16][c * 32 + quad * 8]);
    fa_lo[c] = *(const bf16x8*)(&Alo[m16][c * 32 + quad * 8]);
  }
  float gp[4] = {0.f, 0.f, 0.f, 0.f};
#pragma unroll
  for (int ct = 0; ct < 8; ++ct) {
    bf16x8 bhi[2], blo[2];
    const int wrow = (ct * 16 + m16) * 64 + quad * 8;
#pragma unroll
    for (int c = 0; c < 2; ++c) {
      bhi[c] = *(const bf16x8*)(wg1hi + wrow + c * 32);
      blo[c] = *(const bf16x8*)(wg1lo + wrow + c * 32);
    }
    f32x4 acc = {0.f, 0.f, 0.f, 0.f};
#pragma unroll
    for (int c = 0; c < 2; ++c) {
      acc = __builtin_amdgcn_mfma_f32_16x16x32_bf16(fa_hi[c], bhi[c], acc, 0, 0, 0);
      acc = __builtin_amdgcn_mfma_f32_16x16x32_bf16(fa_hi[c], blo[c], acc, 0, 0, 0);
      acc = __builtin_amdgcn_mfma_f32_16x16x32_bf16(fa_lo[c], bhi[c], acc, 0, 0, 0);
    }
    const int col = ct * 16 + m16;
    const float gb = bg1[col], wg = Wg2v[col];
#pragma unroll
    for (int r = 0; r < 4; ++r) gp[r] += fmaxf(acc[r] + gb, 0.f) * wg;
  }
#pragma unroll
  for (int o = 1; o < 16; o <<= 1)
#pragma unroll
    for (int r = 0; r < 4; ++r) gp[r] += __shfl_xor(gp[r], o, 64);
  if (m16 == 0) {
    const float b2 = bg2v[0];
#pragma unroll
    for (int r = 0; r < 4; ++r) {
      const int node = blockIdx.x * 16 + quad * 4 + r;
      if (node < N) gate[node] = gp[r] + b2;
    }
  }
}

// ---------------- pooling ----------------
__global__ __launch_bounds__(256) void k_pmax(const float* __restrict__ gate,
                                              const int* __restrict__ gstart,
                                              unsigned* __restrict__ gmaxu) {
  __shared__ unsigned red[256];
  const int g = blockIdx.x / CPB;
  const int c = blockIdx.x % CPB;
  const int lo = gstart[g], hi = gstart[g + 1];
  const int len = hi - lo;
  const int b0 = lo + (int)(((long long)len * c) / CPB);
  const int b1 = lo + (int)(((long long)len * (c + 1)) / CPB);
  unsigned mx = 0u;
  for (int i = b0 + threadIdx.x; i < b1; i += 256) mx = max(mx, fenc(gate[i]));
  red[threadIdx.x] = mx;
  __syncthreads();
  for (int o = 128; o; o >>= 1) {
    if (threadIdx.x < o)
      red[threadIdx.x] = max(red[threadIdx.x], red[threadIdx.x + o]);
    __syncthreads();
  }
  if (threadIdx.x == 0 && red[0] != 0u) atomicMax(&gmaxu[g], red[0]);
}

__global__ __launch_bounds__(256) void k_psum(const float* __restrict__ gate,
                                              const float* __restrict__ h3,
                                              const unsigned* __restrict__ gmaxu,
                                              const int* __restrict__ gstart,
                                              float* __restrict__ pooledw,
                                              float* __restrict__ ssum) {
  __shared__ float accs[4][64];
  __shared__ float ses[4];
  const int g = blockIdx.x / CPB;
  const int c = blockIdx.x % CPB;
  const int lo = gstart[g], hi = gstart[g + 1];
  const int len = hi - lo;
  const int b0 = lo + (int)(((long long)len * c) / CPB);
  const int b1 = lo + (int)(((long long)len * (c + 1)) / CPB);
  const int wave = threadIdx.x >> 6, lane = threadIdx.x & 63;
  const float m = fdec(gmaxu[g]);
  float acc = 0.f, se = 0.f;
  for (int i = b0 + wave; i < b1; i += 4) {
    float e = expf(gate[i] - m);
    acc += e * h3[(size_t)i * 64 + lane];
    se += e;
  }
  accs[wave][lane] = acc;
  if (lane == 0) ses[wave] = se;
  __syncthreads();
  if (threadIdx.x < 64) {
    float a = accs[0][threadIdx.x] + accs[1][threadIdx.x] +
              accs[2][threadIdx.x] + accs[3][threadIdx.x];
    if (a != 0.f) atomicAdd(&pooledw[g * 64 + threadIdx.x], a);
  }
  if (threadIdx.x == 64) {
    float s = ses[0] + ses[1] + ses[2] + ses[3];
    if (s != 0.f) atomicAdd(&ssum[g], s);
  }
}

// ---------------- head MLP ----------------
__global__ __launch_bounds__(256) void k_head(const float* __restrict__ pooledw,
                                              const float* __restrict__ ssum,
                                              const float* __restrict__ Wm1,
                                              const float* __restrict__ bm1,
                                              const float* __restrict__ Wm2,
                                              const float* __restrict__ bm2,
                                              float* __restrict__ out) {
  __shared__ float P[64 * 64];
  __shared__ float T[64 * 128];
  int tid = threadIdx.x;
  for (int i = tid; i < 4096; i += 256) {
    float s = ssum[i >> 6];
    P[i] = pooledw[i] * ((s > 0.f) ? 1.0f / s : 0.f);
  }
  __syncthreads();
  for (int e = tid; e < 8192; e += 256) {
    int r = e >> 7, c = e & 127;
    float a = bm1[c];
    for (int k = 0; k < 64; ++k) a += P[r * 64 + k] * Wm1[k * 128 + c];
    T[e] = fmaxf(a, 0.f);
  }
  __syncthreads();
  for (int e = tid; e < 4096; e += 256) {
    int r = e >> 6, c = e & 63;
    float a = bm2[c];
    for (int k = 0; k < 128; ++k) a += T[r * 128 + k] * Wm2[k * 64 + c];
    out[e] = a;
  }
}

extern "C" void kernel_launch(void* const* d_in, const int* in_sizes, int n_in,
                              void* d_out, int out_size, void* d_ws,
                              size_t ws_size, hipStream_t stream) {
  const int N = NN, E = EE;
  const float* x = (const float*)d_in[0];
  const int* ei = (const int*)d_in[1];
  const int* batch = (const int*)d_in[2];
  const float* W1 = (const float*)d_in[3];
  const float* b1 = (const float*)d_in[4];
  const float* W2 = (const float*)d_in[5];
  const float* b2 = (const float*)d_in[6];
  const float* W3 = (const float*)d_in[7];
  const float* b3 = (const float*)d_in[8];
  const float* g1 = (const float*)d_in[9];
  const float* beta1 = (const float*)d_in[10];
  const float* g2 = (const float*)d_in[11];
  const float* beta2 = (const float*)d_in[12];
  const float* mean1 = (const float*)d_in[13];
  const float* var1 = (const float*)d_in[14];
  const float* mean2 = (const float*)d_in[15];
  const float* var2 = (const float*)d_in[16];
  const float* Wg1 = (const float*)d_in[17];
  const float* bg1 = (const float*)d_in[18];
  const float* Wg2 = (const float*)d_in[19];
  const float* bg2 = (const float*)d_in[20];
  const float* Wm1 = (const float*)d_in[21];
  const float* bm1 = (const float*)d_in[22];
  const float* Wm2 = (const float*)d_in[23];
  const float* bm2 = (const float*)d_in[24];
  float* out = (float*)d_out;

  const int* src = ei;
  const int* dst = ei + E;

  char* wsb = (char*)d_ws;
  size_t off = 0;
  auto alloc = [&](size_t elems) -> void* {
    void* p = wsb + off;
    off += elems * 4;
    return p;
  };
  int* rowstart = (int*)alloc(N + 4);
  int* eidx = (int*)alloc(E);
  int2* pairs = (int2*)alloc((size_t)E * 2);
  int* bhist = (int*)alloc(NBLK * 256 + 256);
  int* btot = (int*)alloc(256);
  int* bstart = (int*)alloc(256);
  float* dinv = (float*)alloc(N);
  float* gate = (float*)alloc(N);
  __half* hbuf = (__half*)alloc((size_t)N * 64);  // fp16 N x 128 plane
  short* ahi_p = (short*)alloc((size_t)N * 64);   // bf16-hi N x 128 plane
  short* alo_p = (short*)alloc((size_t)N * 64);   // bf16-lo N x 128 plane
  float* fbuf = (float*)alloc((size_t)N * 64);    // fp32 N x 64 (h3)
  short* wt = (short*)alloc(49152);
  float* bn1s = (float*)alloc(128);
  float* bn1h = (float*)alloc(128);
  float* bn2s = (float*)alloc(128);
  float* bn2h = (float*)alloc(128);
  float* pooledw = (float*)alloc(GG * 64);
  float* ssum = (float*)alloc(GG);
  unsigned* gmaxu = (unsigned*)alloc(GG);
  int* gstart = (int*)alloc(GG + 4);
  (void)ws_size;
  (void)n_in;
  (void)in_sizes;
  (void)out_size;

  // CSR build
  k_bhist<<<NBLK, 256, 0, stream>>>(dst, bhist, E);
  k_bscan1<<<256, 256, 0, stream>>>(bhist, btot);
  k_bscan2<<<1, 256, 0, stream>>>(btot, bstart);
  k_bscat<<<NBLK, 256, 0, stream>>>(src, dst, bhist, bstart, pairs, E);
  k_bfill<<<NBUCK, 256, 0, stream>>>(pairs, bstart, rowstart, eidx, dinv, N, E);

  // fused prep (wsplit + bnprep + gbounds + pool zero)
  k_prep<<<194, 256, 0, stream>>>(W1, W2, W3, Wg1, wt, g1, beta1, mean1, var1,
                                  g2, beta2, mean2, var2, bn1s, bn1h, bn2s,
                                  bn2h, batch, gstart, pooledw, N);

  const int gbb = (N + 127) / 128;
  const int ab128 = (N + 7) / 8;
  const int ab16 = (N + 15) / 16;

  // Layer 1
  k_mgemm1<<<dim3(gbb, 2), 256, 0, stream>>>(x, nullptr, nullptr, wt,
                                             wt + 16384, dinv, hbuf, N);
  k_agg1<<<ab128, 256, 0, stream>>>(hbuf, rowstart, eidx, dinv, b1, bn1s,
                                    bn1h, nullptr, ahi_p, alo_p, N);

  // Layer 2
  k_mgemm2<<<dim3(gbb, 2), 256, 0, stream>>>(nullptr, ahi_p, alo_p, wt + 32768,
                                             wt + 49152, dinv, hbuf, N);
  k_agg2<<<ab128, 256, 0, stream>>>(hbuf, rowstart, eidx, dinv, b2, bn2s,
                                    bn2h, nullptr, ahi_p, alo_p, N);

  // Layer 3 (M=64) + fused gate head
  k_mgemm3<<<dim3(gbb, 1), 256, 0, stream>>>(nullptr, ahi_p, alo_p, wt + 65536,
                                             wt + 73728, dinv, hbuf, N);
  k_agg3g<<<ab16, 256, 0, stream>>>(hbuf, rowstart, eidx, dinv, b3,
                                    wt + 81920, wt + 90112, bg1, Wg2, bg2,
                                    fbuf, gate, N);

  // softmax pooling
  k_pmax<<<GG * CPB, 256, 0, stream>>>(gate, gstart, gmaxu);
  k_psum<<<GG * CPB, 256, 0, stream>>>(gate, fbuf, gmaxu, gstart, pooledw,
                                       ssum);

  // head MLP
  k_head<<<1, 256, 0, stream>>>(pooledw, ssum, Wm1, bm1, Wm2, bm2, out);
}